// Round 1
// baseline (168.299 us; speedup 1.0000x reference)
//
#include <hip/hip_runtime.h>

#define NTOK 16384
#define DIM 256
#define NEXP 8
#define HID 512
#define CAP 5120      // per-expert slot capacity
#define CSTRIDE 16    // counts[e*CSTRIDE]: 64B apart

typedef unsigned short ushort_t;
typedef short bf16x8 __attribute__((ext_vector_type(8)));
typedef float f32x4 __attribute__((ext_vector_type(4)));

static __device__ __forceinline__ ushort_t f2bf(float f) {
    unsigned int u = __float_as_uint(f);
    unsigned int r = (u + 0x7FFFu + ((u >> 16) & 1u)) >> 16;
    return (ushort_t)r;
}
static __device__ __forceinline__ float bf2f(ushort_t u) {
    unsigned int x = ((unsigned int)u) << 16;
    return __uint_as_float(x);
}
// tanh-form GELU, exp2-folded + fast rcp: ~7 VALU ops, max |err| ~1e-3
static __device__ __forceinline__ float gelu_fast(float v) {
    float v2 = v * v;
    float u = v * __builtin_fmaf(v2, -0.1029407079f, -2.3022090196f);
    float e = __builtin_amdgcn_exp2f(u);
    return v * __builtin_amdgcn_rcpf(1.0f + e);
}

// ---------------- kernel P: fused {weight transpose fp32->bf16} + {router + X->bf16} ----
// blocks [0,512): transpose role (independent of router); blocks [512,768): router role.
// Fusing lets the HBM-bound transpose overlap the VALU/LDS-bound router.
struct RouterSmem {
    float xs[64][257];
    float lg[64][8];
    int te0[64], te1[64], lo0[64], lo1[64];
    float tw0[64], tw1[64];
    int lcnt[NEXP], gbase[NEXP];
};
union PrepSmem {
    ushort_t tile[64][72];   // transpose role (9.2KB)
    RouterSmem r;            // router role (~69.5KB)
};

__global__ void k_prep(const float* __restrict__ X, const float* __restrict__ Wg,
                       const float* __restrict__ w1, const float* __restrict__ w2,
                       ushort_t* __restrict__ w1t, ushort_t* __restrict__ w2t,
                       int* counts, int* tok_list, int* inv_idx, float* inv_w,
                       ushort_t* __restrict__ Xb) {
    __shared__ PrepSmem sm;
    int b = blockIdx.x;
    int tid = threadIdx.x;
    if (b < 512) {
        // ---- transpose role ----
        const float* src; ushort_t* dst; int R, C, e, t;
        if (b < 256) { e = b >> 5; t = b & 31; src = w1; dst = w1t + e * DIM * HID; R = DIM; C = HID; }
        else { int bb = b - 256; e = bb >> 5; t = bb & 31; src = w2; dst = w2t + e * DIM * HID; R = HID; C = DIM; }
        size_t ebase = (size_t)e * DIM * HID;
        int tilesC = C >> 6;
        int rt = t / tilesC, ct = t % tilesC;
        for (int i = 0; i < 16; i++) {
            int flat = i * 256 + tid;
            int lr = flat >> 6, lc = flat & 63;
            sm.tile[lr][lc] = f2bf(src[ebase + (size_t)(rt * 64 + lr) * C + ct * 64 + lc]);
        }
        __syncthreads();
        for (int i = 0; i < 16; i++) {
            int flat = i * 256 + tid;
            int lr = flat >> 6, lc = flat & 63;
            dst[(ct * 64 + lr) * R + rt * 64 + lc] = sm.tile[lc][lr];
        }
        return;
    }
    // ---- router role ----
    b -= 512;
    int tok0 = b * 64;
    if (tid < NEXP) sm.r.lcnt[tid] = 0;
    for (int i = 0; i < 8; i++) {
        int flat = i * 256 + tid;
        int r = flat >> 5, c8 = (flat & 31) << 3;
        const float* row = X + (size_t)(tok0 + r) * DIM + c8;
        float4 a = *(const float4*)row;
        float4 bb = *(const float4*)(row + 4);
        sm.r.xs[r][c8 + 0] = a.x; sm.r.xs[r][c8 + 1] = a.y; sm.r.xs[r][c8 + 2] = a.z; sm.r.xs[r][c8 + 3] = a.w;
        sm.r.xs[r][c8 + 4] = bb.x; sm.r.xs[r][c8 + 5] = bb.y; sm.r.xs[r][c8 + 6] = bb.z; sm.r.xs[r][c8 + 7] = bb.w;
    }
    __syncthreads();
    for (int i = 0; i < 8; i++) {
        int flat = i * 256 + tid;
        int r = flat >> 5, c8 = (flat & 31) << 3;
        ushort_t pk[8];
#pragma unroll
        for (int j = 0; j < 8; j++) pk[j] = f2bf(sm.r.xs[r][c8 + j]);
        *(int4*)(Xb + (size_t)(tok0 + r) * DIM + c8) = *(const int4*)pk;
    }
    int tl = tid & 63, pair = tid >> 6;
    float l0 = 0.f, l1 = 0.f;
    for (int d = 0; d < DIM; d++) {
        float x = sm.r.xs[tl][d];
        l0 += x * Wg[d * NEXP + 2 * pair];
        l1 += x * Wg[d * NEXP + 2 * pair + 1];
    }
    sm.r.lg[tl][2 * pair] = l0; sm.r.lg[tl][2 * pair + 1] = l1;
    __syncthreads();
    if (tid < 64) {
        float best = -1e30f; int bi = 0;
#pragma unroll
        for (int e = 0; e < NEXP; e++) { float v = sm.r.lg[tid][e]; if (v > best) { best = v; bi = e; } }
        float best2 = -1e30f; int bi2 = 0;
#pragma unroll
        for (int e = 0; e < NEXP; e++) { if (e == bi) continue; float v = sm.r.lg[tid][e]; if (v > best2) { best2 = v; bi2 = e; } }
        float ed = __expf(best2 - best);
        sm.r.te0[tid] = bi; sm.r.te1[tid] = bi2;
        sm.r.tw0[tid] = 1.0f / (1.0f + ed);
        sm.r.tw1[tid] = ed / (1.0f + ed);
        sm.r.lo0[tid] = atomicAdd(&sm.r.lcnt[bi], 1);
        sm.r.lo1[tid] = atomicAdd(&sm.r.lcnt[bi2], 1);
    }
    __syncthreads();
    if (tid < NEXP) sm.r.gbase[tid] = atomicAdd(&counts[tid * CSTRIDE], sm.r.lcnt[tid]);
    __syncthreads();
    if (tid < 64) {
        int token = tok0 + tid;
        int e0 = sm.r.te0[tid], e1 = sm.r.te1[tid];
        int p0 = sm.r.gbase[e0] + sm.r.lo0[tid]; if (p0 >= CAP) p0 = CAP - 1;
        int p1 = sm.r.gbase[e1] + sm.r.lo1[tid]; if (p1 >= CAP) p1 = CAP - 1;
        tok_list[e0 * CAP + p0] = token;
        tok_list[e1 * CAP + p1] = token;
        inv_idx[token * 2]     = (e0 << 16) | p0;  inv_w[token * 2]     = sm.r.tw0[tid];
        inv_idx[token * 2 + 1] = (e1 << 16) | p1;  inv_w[token * 2 + 1] = sm.r.tw1[tid];
    }
}

// ---------------- kernel M1: GEMM1 + GELU -> hb  (tf=2: 2 MFMA per LDS weight read) ----
// grid: e(8) x [hq(8) x tile(20)] tile-fast. Block 512 thr / 8 waves.
// Wave = 32 tokens x 64 h, K=256 in two 128-chunks (xf regs 32 VGPR at a time).
// LDS traffic halves vs tf=1: each wfr ds_read_b128 feeds 2 MFMAs.
__launch_bounds__(512, 4)
__global__ void k_mlp1(const ushort_t* __restrict__ Xb, const ushort_t* __restrict__ w1t,
                       const float* __restrict__ b1,
                       const int* __restrict__ counts, const int* __restrict__ tok_list,
                       ushort_t* __restrict__ hb) {
    __shared__ ushort_t B1[64 * 264];   // [h][d] 64x256 padded: 33.75KB -> 2 blocks/CU (w/ VGPR<=128)
    int b = blockIdx.x;
    int e = b / 160;                    // 160 = 8 hq * 20 tiles
    int rem = b % 160;
    int hq = rem / 20, tile = rem % 20;
    int count = counts[e * CSTRIDE];
    if (count > CAP) count = CAP;
    int t0 = tile * 256;
    if (t0 >= count) return;

    int tid = threadIdx.x;
    int w = tid >> 6, l = tid & 63, ln = l & 15, q = l >> 4;

    const ushort_t* w1te = w1t + (size_t)e * DIM * HID + (size_t)hq * 64 * DIM;
#pragma unroll
    for (int i = 0; i < 4; i++) {       // 2048 int4 = 64 rows x 32 chunks
        int flat = i * 512 + tid;
        int hr = flat >> 5, c8 = (flat & 31) << 3;
        *(int4*)(B1 + hr * 264 + c8) = *(const int4*)(w1te + hr * DIM + c8);
    }
    // two token fragments per wave: rows [t0+32w+ln] and [+16]
    int arow0 = t0 + 32 * w + ln;
    int arow1 = arow0 + 16;
    int ci0 = (arow0 < count) ? arow0 : (count - 1);
    int ci1 = (arow1 < count) ? arow1 : (count - 1);
    int tk0 = tok_list[e * CAP + ci0];
    int tk1 = tok_list[e * CAP + ci1];
    const ushort_t* xr0 = Xb + (size_t)tk0 * DIM;
    const ushort_t* xr1 = Xb + (size_t)tk1 * DIM;
    __syncthreads();

    f32x4 zf = {0.f, 0.f, 0.f, 0.f};
    f32x4 acc[4][2];
#pragma unroll
    for (int i = 0; i < 4; i++) { acc[i][0] = zf; acc[i][1] = zf; }
#pragma unroll
    for (int kk = 0; kk < 2; kk++) {    // K split in 128-chunks to bound xf VGPRs
        bf16x8 xf0[4], xf1[4];
#pragma unroll
        for (int ks = 0; ks < 4; ks++) {
            xf0[ks] = *(const bf16x8*)(xr0 + kk * 128 + ks * 32 + q * 8);
            xf1[ks] = *(const bf16x8*)(xr1 + kk * 128 + ks * 32 + q * 8);
        }
#pragma unroll
        for (int ks = 0; ks < 4; ks++) {
#pragma unroll
            for (int cf = 0; cf < 4; cf++) {
                bf16x8 wfr = *(const bf16x8*)(B1 + (cf * 16 + ln) * 264 + kk * 128 + ks * 32 + q * 8);
                acc[cf][0] = __builtin_amdgcn_mfma_f32_16x16x32_bf16(wfr, xf0[ks], acc[cf][0], 0, 0, 0);
                acc[cf][1] = __builtin_amdgcn_mfma_f32_16x16x32_bf16(wfr, xf1[ks], acc[cf][1], 0, 0, 0);
            }
        }
    }
    // epilogue: C[h=q*4+r][tok=ln]; bias float4; pack 4 bf16 -> 8B store; two token rows
    size_t base0 = ((size_t)e * CAP + arow0) * HID + hq * 64;
    size_t base1 = ((size_t)e * CAP + arow1) * HID + hq * 64;
#pragma unroll
    for (int cf = 0; cf < 4; cf++) {
        float4 bv = *(const float4*)(b1 + e * HID + hq * 64 + cf * 16 + q * 4);
        ushort4 pk0, pk1;
        pk0.x = f2bf(gelu_fast(acc[cf][0][0] + bv.x));
        pk0.y = f2bf(gelu_fast(acc[cf][0][1] + bv.y));
        pk0.z = f2bf(gelu_fast(acc[cf][0][2] + bv.z));
        pk0.w = f2bf(gelu_fast(acc[cf][0][3] + bv.w));
        pk1.x = f2bf(gelu_fast(acc[cf][1][0] + bv.x));
        pk1.y = f2bf(gelu_fast(acc[cf][1][1] + bv.y));
        pk1.z = f2bf(gelu_fast(acc[cf][1][2] + bv.z));
        pk1.w = f2bf(gelu_fast(acc[cf][1][3] + bv.w));
        *(ushort4*)(hb + base0 + cf * 16 + q * 4) = pk0;
        *(ushort4*)(hb + base1 + cf * 16 + q * 4) = pk1;
    }
}

// ---------------- kernel M2: GEMM2 -> yb  (tf=2, K=512 in four 128-chunks) ----------------
// grid: e(8) x [dq(4) x tile(20)] tile-fast. Block 512 thr / 8 waves.
// Wave = 32 tokens x 64 d.
__launch_bounds__(512, 4)
__global__ void k_mlp2(const ushort_t* __restrict__ hb, const ushort_t* __restrict__ w2t,
                       const float* __restrict__ b2,
                       const int* __restrict__ counts, ushort_t* __restrict__ yb) {
    __shared__ ushort_t B2[64 * 520];   // [d][h] 64x512 padded: 65KB -> 2 blocks/CU
    int b = blockIdx.x;
    int e = b / 80;                     // 80 = 4 dq * 20 tiles
    int rem = b % 80;
    int dq = rem / 20, tile = rem % 20;
    int count = counts[e * CSTRIDE];
    if (count > CAP) count = CAP;
    int t0 = tile * 256;
    if (t0 >= count) return;

    int tid = threadIdx.x;
    int w = tid >> 6, l = tid & 63, ln = l & 15, q = l >> 4;

    const ushort_t* w2te = w2t + (size_t)e * DIM * HID + (size_t)dq * 64 * HID;
#pragma unroll
    for (int i = 0; i < 8; i++) {       // 4096 int4 = 64 rows x 64 chunks
        int flat = i * 512 + tid;
        int dr = flat >> 6, c8 = (flat & 63) << 3;
        *(int4*)(B2 + dr * 520 + c8) = *(const int4*)(w2te + dr * HID + c8);
    }
    int arow0 = t0 + 32 * w + ln;
    int arow1 = arow0 + 16;
    int ci0 = (arow0 < count) ? arow0 : (count - 1);
    int ci1 = (arow1 < count) ? arow1 : (count - 1);
    const ushort_t* hr0 = hb + ((size_t)e * CAP + ci0) * HID;
    const ushort_t* hr1 = hb + ((size_t)e * CAP + ci1) * HID;
    __syncthreads();

    f32x4 zf = {0.f, 0.f, 0.f, 0.f};
    f32x4 acc[4][2];
#pragma unroll
    for (int i = 0; i < 4; i++) { acc[i][0] = zf; acc[i][1] = zf; }
#pragma unroll
    for (int kk = 0; kk < 4; kk++) {
        bf16x8 hf0[4], hf1[4];
#pragma unroll
        for (int ks = 0; ks < 4; ks++) {
            hf0[ks] = *(const bf16x8*)(hr0 + kk * 128 + ks * 32 + q * 8);
            hf1[ks] = *(const bf16x8*)(hr1 + kk * 128 + ks * 32 + q * 8);
        }
#pragma unroll
        for (int ks = 0; ks < 4; ks++) {
#pragma unroll
            for (int cf = 0; cf < 4; cf++) {
                bf16x8 wfr = *(const bf16x8*)(B2 + (cf * 16 + ln) * 520 + kk * 128 + ks * 32 + q * 8);
                acc[cf][0] = __builtin_amdgcn_mfma_f32_16x16x32_bf16(wfr, hf0[ks], acc[cf][0], 0, 0, 0);
                acc[cf][1] = __builtin_amdgcn_mfma_f32_16x16x32_bf16(wfr, hf1[ks], acc[cf][1], 0, 0, 0);
            }
        }
    }
    // epilogue: C[d=q*4+r][tok=ln]; + b2; pack 4 bf16 -> 8B store; two token rows
    size_t yb0 = ((size_t)e * CAP + arow0) * DIM + dq * 64;
    size_t yb1 = ((size_t)e * CAP + arow1) * DIM + dq * 64;
#pragma unroll
    for (int cf = 0; cf < 4; cf++) {
        float4 bv = *(const float4*)(b2 + e * DIM + dq * 64 + cf * 16 + q * 4);
        ushort4 pk0, pk1;
        pk0.x = f2bf(acc[cf][0][0] + bv.x);
        pk0.y = f2bf(acc[cf][0][1] + bv.y);
        pk0.z = f2bf(acc[cf][0][2] + bv.z);
        pk0.w = f2bf(acc[cf][0][3] + bv.w);
        pk1.x = f2bf(acc[cf][1][0] + bv.x);
        pk1.y = f2bf(acc[cf][1][1] + bv.y);
        pk1.z = f2bf(acc[cf][1][2] + bv.z);
        pk1.w = f2bf(acc[cf][1][3] + bv.w);
        *(ushort4*)(yb + yb0 + cf * 16 + q * 4) = pk0;
        *(ushort4*)(yb + yb1 + cf * 16 + q * 4) = pk1;
    }
}

// ---------------- kernel F: combine y0*w0 + y1*w1 -> out (fp32) ----------------
__global__ void k_combine(const ushort_t* __restrict__ yb, const int* __restrict__ inv_idx,
                          const float* __restrict__ inv_w, float* __restrict__ out) {
    int tid = threadIdx.x;
    int n = blockIdx.x * 8 + (tid >> 5);
    int l32 = tid & 31, c8 = l32 << 3;
    int i0 = inv_idx[2 * n], i1 = inv_idx[2 * n + 1];
    float w0 = inv_w[2 * n], w1 = inv_w[2 * n + 1];
    size_t r0 = (size_t)(i0 >> 16) * CAP + (i0 & 0xFFFF);
    size_t r1 = (size_t)(i1 >> 16) * CAP + (i1 & 0xFFFF);
    int4 v0 = *(const int4*)(yb + r0 * DIM + c8);
    int4 v1 = *(const int4*)(yb + r1 * DIM + c8);
    ushort_t* p0 = (ushort_t*)&v0;
    ushort_t* p1 = (ushort_t*)&v1;
    float4 oa, ob;
    oa.x = w0 * bf2f(p0[0]) + w1 * bf2f(p1[0]);
    oa.y = w0 * bf2f(p0[1]) + w1 * bf2f(p1[1]);
    oa.z = w0 * bf2f(p0[2]) + w1 * bf2f(p1[2]);
    oa.w = w0 * bf2f(p0[3]) + w1 * bf2f(p1[3]);
    ob.x = w0 * bf2f(p0[4]) + w1 * bf2f(p1[4]);
    ob.y = w0 * bf2f(p0[5]) + w1 * bf2f(p1[5]);
    ob.z = w0 * bf2f(p0[6]) + w1 * bf2f(p1[6]);
    ob.w = w0 * bf2f(p0[7]) + w1 * bf2f(p1[7]);
    float4* op = (float4*)(out + (size_t)n * DIM + c8);
    op[0] = oa; op[1] = ob;
}

extern "C" void kernel_launch(void* const* d_in, const int* in_sizes, int n_in,
                              void* d_out, int out_size, void* d_ws, size_t ws_size,
                              hipStream_t stream) {
    const float* X  = (const float*)d_in[0];
    const float* Wg = (const float*)d_in[1];
    const float* w1 = (const float*)d_in[2];
    const float* b1 = (const float*)d_in[3];
    const float* w2 = (const float*)d_in[4];
    const float* b2 = (const float*)d_in[5];

    char* ws = (char*)d_ws;
    size_t off = 0;
    int* counts = (int*)(ws + off);        off = 1024;
    int* tok_list = (int*)(ws + off);      off += (size_t)NEXP * CAP * 4;        // 160KB
    int* inv_idx = (int*)(ws + off);       off += (size_t)NTOK * 2 * 4;          // 128KB
    float* inv_w = (float*)(ws + off);     off += (size_t)NTOK * 2 * 4;          // 128KB
    ushort_t* w1t = (ushort_t*)(ws + off); off += (size_t)NEXP * DIM * HID * 2;  // 2MB
    ushort_t* w2t = (ushort_t*)(ws + off); off += (size_t)NEXP * DIM * HID * 2;  // 2MB
    ushort_t* Xb = (ushort_t*)(ws + off);  off += (size_t)NTOK * DIM * 2;        // 8.4MB
    ushort_t* hb = (ushort_t*)(ws + off);  off += (size_t)NEXP * CAP * HID * 2;  // 41.9MB
    ushort_t* yb = (ushort_t*)(ws + off);  off += (size_t)NEXP * CAP * DIM * 2;  // 21MB

    hipMemsetAsync(counts, 0, 1024, stream);   // counts zero (was in k_transpose; racy if fused)
    k_prep<<<768, 256, 0, stream>>>(X, Wg, w1, w2, w1t, w2t, counts, tok_list, inv_idx, inv_w, Xb);
    k_mlp1<<<NEXP * 8 * 20, 512, 0, stream>>>(Xb, w1t, b1, counts, tok_list, hb);
    k_mlp2<<<NEXP * 4 * 20, 512, 0, stream>>>(hb, w2t, b2, counts, yb);
    k_combine<<<2048, 256, 0, stream>>>(yb, inv_idx, inv_w, (float*)d_out);
}

// Round 2
// 163.985 us; speedup vs baseline: 1.0263x; 1.0263x over previous
//
#include <hip/hip_runtime.h>

#define NTOK 16384
#define DIM 256
#define NEXP 8
#define HID 512
#define CAP 5120      // per-expert slot capacity
#define CSTRIDE 16    // counts[e*CSTRIDE]: 64B apart

typedef unsigned short ushort_t;
typedef short bf16x8 __attribute__((ext_vector_type(8)));
typedef float f32x4 __attribute__((ext_vector_type(4)));

static __device__ __forceinline__ ushort_t f2bf(float f) {
    unsigned int u = __float_as_uint(f);
    unsigned int r = (u + 0x7FFFu + ((u >> 16) & 1u)) >> 16;
    return (ushort_t)r;
}
static __device__ __forceinline__ float bf2f(ushort_t u) {
    unsigned int x = ((unsigned int)u) << 16;
    return __uint_as_float(x);
}
// tanh-form GELU, exp2-folded + fast rcp: ~7 VALU ops, max |err| ~1e-3
static __device__ __forceinline__ float gelu_fast(float v) {
    float v2 = v * v;
    float u = v * __builtin_fmaf(v2, -0.1029407079f, -2.3022090196f);
    float e = __builtin_amdgcn_exp2f(u);
    return v * __builtin_amdgcn_rcpf(1.0f + e);
}

// ---------------- kernel T: transpose weights fp32->bf16, zero counts ----------------
__global__ void k_transpose(const float* __restrict__ w1, const float* __restrict__ w2,
                            ushort_t* __restrict__ w1t, ushort_t* __restrict__ w2t,
                            int* __restrict__ counts) {
    __shared__ ushort_t tile[64][72];
    if (blockIdx.x == 0 && threadIdx.x < NEXP * CSTRIDE) counts[threadIdx.x] = 0;
    int b = blockIdx.x;
    const float* src; ushort_t* dst; int R, C, e, t;
    if (b < 256) { e = b >> 5; t = b & 31; src = w1; dst = w1t + e * DIM * HID; R = DIM; C = HID; }
    else { b -= 256; e = b >> 5; t = b & 31; src = w2; dst = w2t + e * DIM * HID; R = HID; C = DIM; }
    size_t ebase = (size_t)e * DIM * HID;
    int tilesC = C >> 6;
    int rt = t / tilesC, ct = t % tilesC;
    for (int i = 0; i < 16; i++) {
        int flat = i * 256 + threadIdx.x;
        int lr = flat >> 6, lc = flat & 63;
        tile[lr][lc] = f2bf(src[ebase + (size_t)(rt * 64 + lr) * C + ct * 64 + lc]);
    }
    __syncthreads();
    for (int i = 0; i < 16; i++) {
        int flat = i * 256 + threadIdx.x;
        int lr = flat >> 6, lc = flat & 63;
        dst[(ct * 64 + lr) * R + rt * 64 + lc] = tile[lc][lr];
    }
}

// ---------------- kernel R: router + X->bf16 canonicalize (fused) ----------------
__global__ void k_router(const float* __restrict__ X, const float* __restrict__ Wg,
                         int* counts, int* tok_list, int* inv_idx, float* inv_w,
                         ushort_t* __restrict__ Xb) {
    __shared__ float xs[64][257];
    __shared__ float lg[64][8];
    __shared__ int te0[64], te1[64], lo0[64], lo1[64];
    __shared__ float tw0[64], tw1[64];
    __shared__ int lcnt[NEXP], gbase[NEXP];
    int tid = threadIdx.x;
    int tok0 = blockIdx.x * 64;
    if (tid < NEXP) lcnt[tid] = 0;
    for (int i = 0; i < 8; i++) {
        int flat = i * 256 + tid;
        int r = flat >> 5, c8 = (flat & 31) << 3;
        const float* row = X + (size_t)(tok0 + r) * DIM + c8;
        float4 a = *(const float4*)row;
        float4 b = *(const float4*)(row + 4);
        xs[r][c8 + 0] = a.x; xs[r][c8 + 1] = a.y; xs[r][c8 + 2] = a.z; xs[r][c8 + 3] = a.w;
        xs[r][c8 + 4] = b.x; xs[r][c8 + 5] = b.y; xs[r][c8 + 6] = b.z; xs[r][c8 + 7] = b.w;
    }
    __syncthreads();
    for (int i = 0; i < 8; i++) {
        int flat = i * 256 + tid;
        int r = flat >> 5, c8 = (flat & 31) << 3;
        ushort_t pk[8];
#pragma unroll
        for (int j = 0; j < 8; j++) pk[j] = f2bf(xs[r][c8 + j]);
        *(int4*)(Xb + (size_t)(tok0 + r) * DIM + c8) = *(const int4*)pk;
    }
    int tl = tid & 63, pair = tid >> 6;
    float l0 = 0.f, l1 = 0.f;
    for (int d = 0; d < DIM; d++) {
        float x = xs[tl][d];
        l0 += x * Wg[d * NEXP + 2 * pair];
        l1 += x * Wg[d * NEXP + 2 * pair + 1];
    }
    lg[tl][2 * pair] = l0; lg[tl][2 * pair + 1] = l1;
    __syncthreads();
    if (tid < 64) {
        float best = -1e30f; int bi = 0;
#pragma unroll
        for (int e = 0; e < NEXP; e++) { float v = lg[tid][e]; if (v > best) { best = v; bi = e; } }
        float best2 = -1e30f; int bi2 = 0;
#pragma unroll
        for (int e = 0; e < NEXP; e++) { if (e == bi) continue; float v = lg[tid][e]; if (v > best2) { best2 = v; bi2 = e; } }
        float ed = __expf(best2 - best);
        te0[tid] = bi; te1[tid] = bi2;
        tw0[tid] = 1.0f / (1.0f + ed);
        tw1[tid] = ed / (1.0f + ed);
        lo0[tid] = atomicAdd(&lcnt[bi], 1);
        lo1[tid] = atomicAdd(&lcnt[bi2], 1);
    }
    __syncthreads();
    if (tid < NEXP) gbase[tid] = atomicAdd(&counts[tid * CSTRIDE], lcnt[tid]);
    __syncthreads();
    if (tid < 64) {
        int token = tok0 + tid;
        int e0 = te0[tid], e1 = te1[tid];
        int p0 = gbase[e0] + lo0[tid]; if (p0 >= CAP) p0 = CAP - 1;
        int p1 = gbase[e1] + lo1[tid]; if (p1 >= CAP) p1 = CAP - 1;
        tok_list[e0 * CAP + p0] = token;
        tok_list[e1 * CAP + p1] = token;
        inv_idx[token * 2]     = (e0 << 16) | p0;  inv_w[token * 2]     = tw0[tid];
        inv_idx[token * 2 + 1] = (e1 << 16) | p1;  inv_w[token * 2 + 1] = tw1[tid];
    }
}

// ---------------- kernel M1: GEMM1 + GELU -> hb  (baseline geometry, tf=2) ----------------
// grid: e(8) x [hq(4) x tile(20)] tile-fast. Block 512 thr / 8 waves.
// Wave = 32 tokens x 128 h (two 16-token frags share every weight ds_read_b128).
// vs baseline: LDS read traffic per MFMA halves; gather/weight traffic unchanged.
__launch_bounds__(512, 4)
__global__ void k_mlp1(const ushort_t* __restrict__ Xb, const ushort_t* __restrict__ w1t,
                       const float* __restrict__ b1,
                       const int* __restrict__ counts, const int* __restrict__ tok_list,
                       ushort_t* __restrict__ hb) {
    __shared__ ushort_t B1[128 * 264];   // [h][d], 67.5KB -> 2 blocks/CU
    int b = blockIdx.x;
    int e = b / 80;                      // 80 = 4 hq * 20 tiles
    int rem = b % 80;
    int hq = rem / 20, tile = rem % 20;
    int count = counts[e * CSTRIDE];
    if (count > CAP) count = CAP;
    int t0 = tile * 256;
    if (t0 >= count) return;

    int tid = threadIdx.x;
    int w = tid >> 6, l = tid & 63, ln = l & 15, q = l >> 4;

    const ushort_t* w1te = w1t + (size_t)e * DIM * HID + (size_t)hq * 128 * DIM;
#pragma unroll
    for (int i = 0; i < 8; i++) {        // 4096 int4 = 128 rows x 32 chunks
        int flat = i * 512 + tid;
        int hr = flat >> 5, c8 = (flat & 31) << 3;
        *(int4*)(B1 + hr * 264 + c8) = *(const int4*)(w1te + hr * DIM + c8);
    }
    // two token fragments per wave: rows [t0+32w+ln] and [+16]
    int arow0 = t0 + 32 * w + ln;
    int arow1 = arow0 + 16;
    int ci0 = (arow0 < count) ? arow0 : (count - 1);
    int ci1 = (arow1 < count) ? arow1 : (count - 1);
    int tk0 = tok_list[e * CAP + ci0];
    int tk1 = tok_list[e * CAP + ci1];
    const ushort_t* xr0 = Xb + (size_t)tk0 * DIM;
    const ushort_t* xr1 = Xb + (size_t)tk1 * DIM;
    __syncthreads();

    f32x4 zf = {0.f, 0.f, 0.f, 0.f};
    f32x4 acc[8][2];                     // 64 VGPR
#pragma unroll
    for (int i = 0; i < 8; i++) { acc[i][0] = zf; acc[i][1] = zf; }
#pragma unroll
    for (int kk = 0; kk < 4; kk++) {     // K=256 in 64-chunks: xf live regs = 16 VGPR
        bf16x8 x0[2], x1[2];
#pragma unroll
        for (int ks = 0; ks < 2; ks++) {
            x0[ks] = *(const bf16x8*)(xr0 + kk * 64 + ks * 32 + q * 8);
            x1[ks] = *(const bf16x8*)(xr1 + kk * 64 + ks * 32 + q * 8);
        }
#pragma unroll
        for (int ks = 0; ks < 2; ks++) {
#pragma unroll
            for (int cf = 0; cf < 8; cf++) {
                bf16x8 wfr = *(const bf16x8*)(B1 + (cf * 16 + ln) * 264 + kk * 64 + ks * 32 + q * 8);
                acc[cf][0] = __builtin_amdgcn_mfma_f32_16x16x32_bf16(wfr, x0[ks], acc[cf][0], 0, 0, 0);
                acc[cf][1] = __builtin_amdgcn_mfma_f32_16x16x32_bf16(wfr, x1[ks], acc[cf][1], 0, 0, 0);
            }
        }
    }
    // epilogue: C[h=q*4+r (in-lane)][tok=ln]; bias float4; pack 4 bf16 -> 8B store; 2 rows
    size_t base0 = ((size_t)e * CAP + arow0) * HID + hq * 128;
    size_t base1 = ((size_t)e * CAP + arow1) * HID + hq * 128;
#pragma unroll
    for (int cf = 0; cf < 8; cf++) {
        float4 bv = *(const float4*)(b1 + e * HID + hq * 128 + cf * 16 + q * 4);
        ushort4 pk0, pk1;
        pk0.x = f2bf(gelu_fast(acc[cf][0][0] + bv.x));
        pk0.y = f2bf(gelu_fast(acc[cf][0][1] + bv.y));
        pk0.z = f2bf(gelu_fast(acc[cf][0][2] + bv.z));
        pk0.w = f2bf(gelu_fast(acc[cf][0][3] + bv.w));
        pk1.x = f2bf(gelu_fast(acc[cf][1][0] + bv.x));
        pk1.y = f2bf(gelu_fast(acc[cf][1][1] + bv.y));
        pk1.z = f2bf(gelu_fast(acc[cf][1][2] + bv.z));
        pk1.w = f2bf(gelu_fast(acc[cf][1][3] + bv.w));
        *(ushort4*)(hb + base0 + cf * 16 + q * 4) = pk0;
        *(ushort4*)(hb + base1 + cf * 16 + q * 4) = pk1;
    }
}

// ---------------- kernel M2: GEMM2 -> yb  (baseline geometry, tf=2) ----------------
// grid: e(8) x [dq(4) x tile(20)] tile-fast. Block 512 thr / 8 waves.
// Wave = 32 tokens x 64 d, K=512 in 64-chunks.
__launch_bounds__(512, 4)
__global__ void k_mlp2(const ushort_t* __restrict__ hb, const ushort_t* __restrict__ w2t,
                       const float* __restrict__ b2,
                       const int* __restrict__ counts, ushort_t* __restrict__ yb) {
    __shared__ ushort_t B2[64 * 520];    // [d][h], 65KB -> 2 blocks/CU
    int b = blockIdx.x;
    int e = b / 80;                      // 80 = 4 dq * 20 tiles
    int rem = b % 80;
    int dq = rem / 20, tile = rem % 20;
    int count = counts[e * CSTRIDE];
    if (count > CAP) count = CAP;
    int t0 = tile * 256;
    if (t0 >= count) return;

    int tid = threadIdx.x;
    int w = tid >> 6, l = tid & 63, ln = l & 15, q = l >> 4;

    const ushort_t* w2te = w2t + (size_t)e * DIM * HID + (size_t)dq * 64 * HID;
#pragma unroll
    for (int i = 0; i < 8; i++) {        // 4096 int4 = 64 rows x 64 chunks
        int flat = i * 512 + tid;
        int dr = flat >> 6, c8 = (flat & 63) << 3;
        *(int4*)(B2 + dr * 520 + c8) = *(const int4*)(w2te + dr * HID + c8);
    }
    int arow0 = t0 + 32 * w + ln;
    int arow1 = arow0 + 16;
    int ci0 = (arow0 < count) ? arow0 : (count - 1);
    int ci1 = (arow1 < count) ? arow1 : (count - 1);
    const ushort_t* hr0 = hb + ((size_t)e * CAP + ci0) * HID;
    const ushort_t* hr1 = hb + ((size_t)e * CAP + ci1) * HID;
    __syncthreads();

    f32x4 zf = {0.f, 0.f, 0.f, 0.f};
    f32x4 acc[4][2];                     // 32 VGPR
#pragma unroll
    for (int i = 0; i < 4; i++) { acc[i][0] = zf; acc[i][1] = zf; }
#pragma unroll
    for (int kk = 0; kk < 8; kk++) {     // K=512 in 64-chunks
        bf16x8 h0[2], h1[2];
#pragma unroll
        for (int ks = 0; ks < 2; ks++) {
            h0[ks] = *(const bf16x8*)(hr0 + kk * 64 + ks * 32 + q * 8);
            h1[ks] = *(const bf16x8*)(hr1 + kk * 64 + ks * 32 + q * 8);
        }
#pragma unroll
        for (int ks = 0; ks < 2; ks++) {
#pragma unroll
            for (int cf = 0; cf < 4; cf++) {
                bf16x8 wfr = *(const bf16x8*)(B2 + (cf * 16 + ln) * 520 + kk * 64 + ks * 32 + q * 8);
                acc[cf][0] = __builtin_amdgcn_mfma_f32_16x16x32_bf16(wfr, h0[ks], acc[cf][0], 0, 0, 0);
                acc[cf][1] = __builtin_amdgcn_mfma_f32_16x16x32_bf16(wfr, h1[ks], acc[cf][1], 0, 0, 0);
            }
        }
    }
    // epilogue: C[d=q*4+r (in-lane)][tok=ln]; + b2; pack 4 bf16 -> 8B store; 2 rows
    size_t yb0 = ((size_t)e * CAP + arow0) * DIM + dq * 64;
    size_t yb1 = ((size_t)e * CAP + arow1) * DIM + dq * 64;
#pragma unroll
    for (int cf = 0; cf < 4; cf++) {
        float4 bv = *(const float4*)(b2 + e * DIM + dq * 64 + cf * 16 + q * 4);
        ushort4 pk0, pk1;
        pk0.x = f2bf(acc[cf][0][0] + bv.x);
        pk0.y = f2bf(acc[cf][0][1] + bv.y);
        pk0.z = f2bf(acc[cf][0][2] + bv.z);
        pk0.w = f2bf(acc[cf][0][3] + bv.w);
        pk1.x = f2bf(acc[cf][1][0] + bv.x);
        pk1.y = f2bf(acc[cf][1][1] + bv.y);
        pk1.z = f2bf(acc[cf][1][2] + bv.z);
        pk1.w = f2bf(acc[cf][1][3] + bv.w);
        *(ushort4*)(yb + yb0 + cf * 16 + q * 4) = pk0;
        *(ushort4*)(yb + yb1 + cf * 16 + q * 4) = pk1;
    }
}

// ---------------- kernel F: combine y0*w0 + y1*w1 -> out (fp32) ----------------
__global__ void k_combine(const ushort_t* __restrict__ yb, const int* __restrict__ inv_idx,
                          const float* __restrict__ inv_w, float* __restrict__ out) {
    int tid = threadIdx.x;
    int n = blockIdx.x * 8 + (tid >> 5);
    int l32 = tid & 31, c8 = l32 << 3;
    int i0 = inv_idx[2 * n], i1 = inv_idx[2 * n + 1];
    float w0 = inv_w[2 * n], w1 = inv_w[2 * n + 1];
    size_t r0 = (size_t)(i0 >> 16) * CAP + (i0 & 0xFFFF);
    size_t r1 = (size_t)(i1 >> 16) * CAP + (i1 & 0xFFFF);
    int4 v0 = *(const int4*)(yb + r0 * DIM + c8);
    int4 v1 = *(const int4*)(yb + r1 * DIM + c8);
    ushort_t* p0 = (ushort_t*)&v0;
    ushort_t* p1 = (ushort_t*)&v1;
    float4 oa, ob;
    oa.x = w0 * bf2f(p0[0]) + w1 * bf2f(p1[0]);
    oa.y = w0 * bf2f(p0[1]) + w1 * bf2f(p1[1]);
    oa.z = w0 * bf2f(p0[2]) + w1 * bf2f(p1[2]);
    oa.w = w0 * bf2f(p0[3]) + w1 * bf2f(p1[3]);
    ob.x = w0 * bf2f(p0[4]) + w1 * bf2f(p1[4]);
    ob.y = w0 * bf2f(p0[5]) + w1 * bf2f(p1[5]);
    ob.z = w0 * bf2f(p0[6]) + w1 * bf2f(p1[6]);
    ob.w = w0 * bf2f(p0[7]) + w1 * bf2f(p1[7]);
    float4* op = (float4*)(out + (size_t)n * DIM + c8);
    op[0] = oa; op[1] = ob;
}

extern "C" void kernel_launch(void* const* d_in, const int* in_sizes, int n_in,
                              void* d_out, int out_size, void* d_ws, size_t ws_size,
                              hipStream_t stream) {
    const float* X  = (const float*)d_in[0];
    const float* Wg = (const float*)d_in[1];
    const float* w1 = (const float*)d_in[2];
    const float* b1 = (const float*)d_in[3];
    const float* w2 = (const float*)d_in[4];
    const float* b2 = (const float*)d_in[5];

    char* ws = (char*)d_ws;
    size_t off = 0;
    int* counts = (int*)(ws + off);        off = 1024;
    int* tok_list = (int*)(ws + off);      off += (size_t)NEXP * CAP * 4;        // 160KB
    int* inv_idx = (int*)(ws + off);       off += (size_t)NTOK * 2 * 4;          // 128KB
    float* inv_w = (float*)(ws + off);     off += (size_t)NTOK * 2 * 4;          // 128KB
    ushort_t* w1t = (ushort_t*)(ws + off); off += (size_t)NEXP * DIM * HID * 2;  // 2MB
    ushort_t* w2t = (ushort_t*)(ws + off); off += (size_t)NEXP * DIM * HID * 2;  // 2MB
    ushort_t* Xb = (ushort_t*)(ws + off);  off += (size_t)NTOK * DIM * 2;        // 8.4MB
    ushort_t* hb = (ushort_t*)(ws + off);  off += (size_t)NEXP * CAP * HID * 2;  // 41.9MB
    ushort_t* yb = (ushort_t*)(ws + off);  off += (size_t)NEXP * CAP * DIM * 2;  // 21MB

    k_transpose<<<512, 256, 0, stream>>>(w1, w2, w1t, w2t, counts);
    k_router<<<256, 256, 0, stream>>>(X, Wg, counts, tok_list, inv_idx, inv_w, Xb);
    k_mlp1<<<NEXP * 4 * 20, 512, 0, stream>>>(Xb, w1t, b1, counts, tok_list, hb);
    k_mlp2<<<NEXP * 4 * 20, 512, 0, stream>>>(hb, w2t, b2, counts, yb);
    k_combine<<<2048, 256, 0, stream>>>(yb, inv_idx, inv_w, (float*)d_out);
}